// Round 5
// baseline (455.485 us; speedup 1.0000x reference)
//
#include <hip/hip_runtime.h>
#include <stdint.h>

#define NNODES 10000
#define NEDGES 100000
#define DNODE 56
#define JTOT 1600
#define HBLK 391   // k_hidden part blocks
#define TBLK 400   // G-transpose part blocks

typedef __attribute__((ext_vector_type(8))) short short8;
typedef __attribute__((ext_vector_type(4))) float floatx4;

__device__ __forceinline__ unsigned short f2bf(float f) {
  unsigned u = __float_as_uint(f);
  u = u + 0x7fffu + ((u >> 16) & 1u);
  return (unsigned short)(u >> 16);
}
__device__ __forceinline__ float bf2f(unsigned short u) {
  return __uint_as_float(((unsigned)u) << 16);
}

__device__ __forceinline__ float mishf(float x) {
  float e = __expf(x);
  float z = 1.f + e; z = z * z;
  float t = (z - 1.f) / (z + 1.f);
  t = (x > 40.f) ? 1.f : t;
  return x * t;
}

// ---- fused: blocks [0,391) h = mish(ea@fc1+b1) + src histogram; [391,791) G = bf16(fc2w^T)
__global__ __launch_bounds__(256) void k_hidtr(const float* __restrict__ ea,
                                               const float* __restrict__ fc1w,
                                               const float* __restrict__ fc1b,
                                               const float* __restrict__ fc2w,
                                               const int* __restrict__ eidx,
                                               int* __restrict__ cntn,
                                               unsigned short* __restrict__ hb,
                                               unsigned short* __restrict__ G) {
  int bid = blockIdx.x;
  if (bid >= HBLK) {
    int idx = (bid - HBLK) * 256 + threadIdx.x;
    if (idx < 64 * JTOT) {
      int j = idx >> 6, k = idx & 63;
      G[idx] = f2bf(fc2w[k * JTOT + j]);
    }
    return;
  }
  int e = bid * 256 + threadIdx.x;
  if (e >= NEDGES) return;
  atomicAdd(&cntn[eidx[e]], 1);
  float a[64];
  const float4* row = (const float4*)(ea + (size_t)e * 64);
  #pragma unroll
  for (int i = 0; i < 16; i++) {
    float4 t = row[i];
    a[4*i] = t.x; a[4*i+1] = t.y; a[4*i+2] = t.z; a[4*i+3] = t.w;
  }
  for (int jb = 0; jb < 64; jb += 8) {
    float acc[8];
    #pragma unroll
    for (int i = 0; i < 8; i++) acc[i] = fc1b[jb + i];
    #pragma unroll
    for (int k = 0; k < 64; k++) {
      #pragma unroll
      for (int i = 0; i < 8; i++) acc[i] = fmaf(a[k], fc1w[k*64 + jb + i], acc[i]);
    }
    unsigned pk[4];
    #pragma unroll
    for (int i = 0; i < 4; i++) {
      unsigned lo = f2bf(mishf(acc[2*i]));
      unsigned hi = f2bf(mishf(acc[2*i+1]));
      pk[i] = lo | (hi << 16);
    }
    *(uint4*)(hb + (size_t)e*64 + jb) = make_uint4(pk[0], pk[1], pk[2], pk[3]);
  }
}

// ---- single-wave barrier-free scan: offs/cursor from cntn
__global__ __launch_bounds__(64) void k_scan(const int* __restrict__ cntn,
                                             int* __restrict__ offs,
                                             int* __restrict__ cursor) {
  const int PER = 157;                  // 157*64 = 10048 >= 10000
  int lane = threadIdx.x;
  int base = lane * PER;
  int s = 0;
  for (int i = 0; i < PER; i++) {
    int idx = base + i;
    if (idx < NNODES) s += cntn[idx];
  }
  int incl = s;
  #pragma unroll
  for (int o = 1; o < 64; o <<= 1) {
    int v = __shfl_up(incl, o);
    if (lane >= o) incl += v;
  }
  int run = incl - s;
  for (int i = 0; i < PER; i++) {
    int idx = base + i;
    if (idx < NNODES) {
      offs[idx] = run; cursor[idx] = run;
      run += cntn[idx];
    }
  }
  if (lane == 63) offs[NNODES] = run;
}

// ---- fused GEMM2 + tensor product. Block = 2 waves x 32 edges. Barrier-free K-loop:
// A-frags streamed straight from L2 (prefetch 1 pair), coefs in per-wave bf16 LDS,
// b2 in block LDS (single barrier at top). Direct-store epilogue.
__global__ __launch_bounds__(128, 4) void k_tp(
    const unsigned short* __restrict__ hb,
    const unsigned short* __restrict__ G,
    const float* __restrict__ fc2b,
    const int* __restrict__ eidx,
    const float* __restrict__ node_attr,
    const float* __restrict__ edge_sh,
    int* __restrict__ cursor,
    float* __restrict__ tp) {
  __shared__ float b2s[JTOT];
  __shared__ unsigned short wls[2][64 * 32];   // per-wave coef table (bf16): row u x 32 edges
  __shared__ int pos_s[2][32];
  const int tid = threadIdx.x;
  const int wave = tid >> 6, lane = tid & 63;
  for (int i = tid; i < JTOT; i += 128) b2s[i] = fc2b[i];

  const int e0w = blockIdx.x * 64 + wave * 32;
  unsigned short* Wt = &wls[wave][0];
  {
    int el = lane & 31, hh = lane >> 5;
    int e = e0w + el;
    bool valid = e < NEDGES;
    int dst = valid ? eidx[NEDGES + e] : 0;
    const float* na = node_attr + (size_t)dst * DNODE;
    if (hh == 0) {
      pos_s[wave][el] = valid ? atomicAdd(&cursor[eidx[e]], 1) : 0;
      #pragma unroll
      for (int u = 0; u < 32; u += 4) {
        float4 t = valid ? *(const float4*)(na + u) : make_float4(0.f,0.f,0.f,0.f);
        Wt[(u+0)*32 + el] = f2bf(t.x);
        Wt[(u+1)*32 + el] = f2bf(t.y);
        Wt[(u+2)*32 + el] = f2bf(t.z);
        Wt[(u+3)*32 + el] = f2bf(t.w);
      }
    } else {
      float4 sh = valid ? *(const float4*)(edge_sh + 4*(size_t)e) : make_float4(0.f,0.f,0.f,0.f);
      const float rs3 = 0.57735026918962576f;
      #pragma unroll
      for (int u = 0; u < 8; u++) {
        float v0 = valid ? na[32 + u*3 + 0] : 0.f;
        float v1 = valid ? na[32 + u*3 + 1] : 0.f;
        float v2 = valid ? na[32 + u*3 + 2] : 0.f;
        Wt[(32 + u*3 + 0)*32 + el] = f2bf(v0);
        Wt[(32 + u*3 + 1)*32 + el] = f2bf(v1);
        Wt[(32 + u*3 + 2)*32 + el] = f2bf(v2);
        Wt[(56 + u)*32 + el] = f2bf((v0*sh.y + v1*sh.z + v2*sh.w) * rs3);
      }
    }
  }
  __syncthreads();   // b2s ready (Wt is per-wave, needs no barrier)

  const int col = lane & 15, rg = lane >> 4, rgh = rg >> 1;
  float sh0c[2], sh1c[2][3];
  bool vld[2];
  short8 bfrag[2][2];
  const short8 zfrag = {0,0,0,0,0,0,0,0};
  #pragma unroll
  for (int nt = 0; nt < 2; nt++) {
    int e = e0w + nt*16 + col;
    bool v = e < NEDGES; vld[nt] = v;
    if (v) {
      float4 sh = *(const float4*)(edge_sh + 4*(size_t)e);
      sh0c[nt] = sh.x; sh1c[nt][0] = sh.y; sh1c[nt][1] = sh.z; sh1c[nt][2] = sh.w;
      const unsigned short* hp = hb + (size_t)e * 64;
      bfrag[nt][0] = *(const short8*)(hp + rg*8);
      bfrag[nt][1] = *(const short8*)(hp + 32 + rg*8);
    } else {
      sh0c[nt] = 0.f; sh1c[nt][0] = sh1c[nt][1] = sh1c[nt][2] = 0.f;
      bfrag[nt][0] = zfrag; bfrag[nt][1] = zfrag;
    }
  }

  float sacc[2][8], vacc[2][12];
  #pragma unroll
  for (int nt = 0; nt < 2; nt++) {
    #pragma unroll
    for (int i = 0; i < 8; i++) sacc[nt][i] = 0.f;
    #pragma unroll
    for (int i = 0; i < 12; i++) vacc[nt][i] = 0.f;
  }

  // A-frag pair load: tiles jt=2pp, 2pp+1 (4 x 16B from global/L2)
  auto ldpair = [&](int pp, short8& f0, short8& f1, short8& f2, short8& f3) {
    const unsigned short* q = G + (((pp*32) + col) << 6) + rg*8;
    f0 = *(const short8*)q;
    f1 = *(const short8*)(q + 32);
    f2 = *(const short8*)(q + 1024);
    f3 = *(const short8*)(q + 1024 + 32);
  };

  short8 c0, c1, c2, c3, n0, n1, n2, n3;
  ldpair(0, c0, c1, c2, c3);

  #pragma unroll 1
  for (int pp = 0; pp < 50; pp++) {
    if (pp < 49) ldpair(pp + 1, n0, n1, n2, n3);
    const int jt0 = 2*pp;
    float4 bb0 = *(const float4*)&b2s[jt0*16 + rg*4];
    float4 bb1 = *(const float4*)&b2s[(jt0+1)*16 + rg*4];
    floatx4 acc0[2], acc1[2];
    #pragma unroll
    for (int nt = 0; nt < 2; nt++) {
      floatx4 a0 = {bb0.x, bb0.y, bb0.z, bb0.w};
      a0 = __builtin_amdgcn_mfma_f32_16x16x32_bf16(c0, bfrag[nt][0], a0, 0, 0, 0);
      a0 = __builtin_amdgcn_mfma_f32_16x16x32_bf16(c1, bfrag[nt][1], a0, 0, 0, 0);
      acc0[nt] = a0;
      floatx4 a1 = {bb1.x, bb1.y, bb1.z, bb1.w};
      a1 = __builtin_amdgcn_mfma_f32_16x16x32_bf16(c2, bfrag[nt][0], a1, 0, 0, 0);
      a1 = __builtin_amdgcn_mfma_f32_16x16x32_bf16(c3, bfrag[nt][1], a1, 0, 0, 0);
      acc1[nt] = a1;
    }
    if (pp < 32) {                     // w1: u = pp, tile0 -> sacc[0..3], tile1 -> sacc[4..7]
      #pragma unroll
      for (int nt = 0; nt < 2; nt++) {
        float cf = bf2f(Wt[pp*32 + nt*16 + col]) * sh0c[nt];
        #pragma unroll
        for (int r = 0; r < 4; r++) {
          sacc[nt][r]   = fmaf(cf, acc0[nt][r], sacc[nt][r]);
          sacc[nt][4+r] = fmaf(cf, acc1[nt][r], sacc[nt][4+r]);
        }
      }
    } else if (pp < 34) {              // w2: tiles jt0,jt0+1 with u = (jt-64)*2+rgh
      const int u0 = (jt0 - 64)*2 + rgh, u1 = u0 + 2;
      #pragma unroll
      for (int nt = 0; nt < 2; nt++) {
        #pragma unroll
        for (int q = 0; q < 3; q++) {
          float cf0 = bf2f(Wt[(32 + u0*3 + q)*32 + nt*16 + col]) * sh0c[nt];
          float cf1 = bf2f(Wt[(32 + u1*3 + q)*32 + nt*16 + col]) * sh0c[nt];
          #pragma unroll
          for (int r = 0; r < 4; r++) {
            vacc[nt][q*4+r] = fmaf(cf0, acc0[nt][r], vacc[nt][q*4+r]);
            vacc[nt][q*4+r] = fmaf(cf1, acc1[nt][r], vacc[nt][q*4+r]);
          }
        }
      }
    } else if (pp < 42) {              // w3: u = (jt-68)*2+rgh
      const int u0 = (jt0 - 68)*2 + rgh, u1 = u0 + 2;
      #pragma unroll
      for (int nt = 0; nt < 2; nt++) {
        float sv0 = bf2f(Wt[u0*32 + nt*16 + col]);
        float sv1 = bf2f(Wt[u1*32 + nt*16 + col]);
        #pragma unroll
        for (int q = 0; q < 3; q++) {
          float cf0 = sv0 * sh1c[nt][q];
          float cf1 = sv1 * sh1c[nt][q];
          #pragma unroll
          for (int r = 0; r < 4; r++) {
            vacc[nt][q*4+r] = fmaf(cf0, acc0[nt][r], vacc[nt][q*4+r]);
            vacc[nt][q*4+r] = fmaf(cf1, acc1[nt][r], vacc[nt][q*4+r]);
          }
        }
      }
    } else {                           // w4: u = pp-42, same sacc slots as w1
      const int u = pp - 42;
      #pragma unroll
      for (int nt = 0; nt < 2; nt++) {
        float cf = bf2f(Wt[(56 + u)*32 + nt*16 + col]);
        #pragma unroll
        for (int r = 0; r < 4; r++) {
          sacc[nt][r]   = fmaf(cf, acc0[nt][r], sacc[nt][r]);
          sacc[nt][4+r] = fmaf(cf, acc1[nt][r], sacc[nt][4+r]);
        }
      }
    }
    c0 = n0; c1 = n1; c2 = n2; c3 = n3;
  }

  // ---- epilogue: direct stores
  const float ascale = 0.15811388300841897f;   // 1/sqrt(40)
  #pragma unroll
  for (int nt = 0; nt < 2; nt++) {
    int el = nt*16 + col;
    float* rowp = tp + (size_t)pos_s[wave][el] * DNODE;
    if (vld[nt]) {
      #pragma unroll
      for (int p = 0; p < 2; p++) {
        float4 v = make_float4(ascale*sacc[nt][p*4+0], ascale*sacc[nt][p*4+1],
                               ascale*sacc[nt][p*4+2], ascale*sacc[nt][p*4+3]);
        *(float4*)(rowp + p*16 + rg*4) = v;
      }
    }
    float vtot[12];
    #pragma unroll
    for (int k = 0; k < 12; k++)
      vtot[k] = (vacc[nt][k] + __shfl_xor(vacc[nt][k], 32)) * ascale;
    if (rg < 2 && vld[nt]) {
      float tmp[12];
      #pragma unroll
      for (int q = 0; q < 3; q++)
        #pragma unroll
        for (int r = 0; r < 4; r++) tmp[r*3 + q] = vtot[q*4 + r];
      #pragma unroll
      for (int j = 0; j < 3; j++)
        *(float4*)(rowp + 32 + (rg & 1)*12 + j*4) = *(float4*)&tmp[j*4];
    }
  }
}

// ---- per-node mean + residual + BN partials (contiguous CSR rows)
__global__ __launch_bounds__(256) void k_gather(const float* __restrict__ tp,
                                                const int* __restrict__ offs,
                                                const float* __restrict__ node_attr,
                                                float* __restrict__ pre,
                                                float* __restrict__ pstat) {
  __shared__ float redS[4*64], redQ[4*64];
  int t = threadIdx.x, wave = t >> 6, lane = t & 63;
  int gw = blockIdx.x * 4 + wave;
  const int W = 640 * 4;
  int off = (lane < DNODE) ? lane : 0;
  float ssum = 0.f, ssq = 0.f;
  for (int n = gw; n < NNODES; n += W) {
    int beg = offs[n], end = offs[n+1];
    float acc = 0.f;
    int i = beg;
    for (; i + 4 <= end; i += 4) {
      float v0 = tp[(size_t)(i+0)*DNODE + off];
      float v1 = tp[(size_t)(i+1)*DNODE + off];
      float v2 = tp[(size_t)(i+2)*DNODE + off];
      float v3 = tp[(size_t)(i+3)*DNODE + off];
      acc += (v0 + v1) + (v2 + v3);
    }
    for (; i < end; i++) acc += tp[(size_t)i*DNODE + off];
    int c = end - beg; if (c < 1) c = 1;
    float m = acc / (float)c + node_attr[(size_t)n*DNODE + off];
    if (lane < DNODE) { pre[(size_t)n*DNODE + lane] = m; ssum += m; ssq += m*m; }
  }
  redS[wave*64 + lane] = ssum;
  redQ[wave*64 + lane] = ssq;
  __syncthreads();
  if (wave == 0 && lane < DNODE) {
    float a = redS[lane] + redS[64+lane] + redS[128+lane] + redS[192+lane];
    float b = redQ[lane] + redQ[64+lane] + redQ[128+lane] + redQ[192+lane];
    pstat[(size_t)blockIdx.x*112 + lane] = a;
    pstat[(size_t)blockIdx.x*112 + 56 + lane] = b;
  }
}

__global__ __launch_bounds__(256) void k_stats(const float* __restrict__ pstat,
                                               float* __restrict__ stats) {
  int f = blockIdx.x * 4 + (threadIdx.x >> 6);
  int lane = threadIdx.x & 63;
  float v = 0.f;
  for (int b = lane; b < 640; b += 64) v += pstat[(size_t)b*112 + f];
  #pragma unroll
  for (int o = 32; o; o >>= 1) v += __shfl_xor(v, o);
  if (lane == 0) stats[f] = v;
}

__global__ __launch_bounds__(256) void k_norm(const float* __restrict__ pre,
                                              const float* __restrict__ stats,
                                              const float* __restrict__ gs,
                                              const float* __restrict__ bs,
                                              const float* __restrict__ gv,
                                              float* __restrict__ out) {
  int idx = blockIdx.x * 256 + threadIdx.x;
  if (idx >= NNODES * DNODE) return;
  int n = idx / DNODE;
  int d = idx - n * DNODE;
  float val = pre[idx];
  const float invN = 1.f / (float)NNODES;
  float res;
  if (d < 32) {
    float mu = stats[d] * invN;
    float var = stats[56 + d] * invN - mu * mu;
    res = (val - mu) * rsqrtf(var + 1e-4f) * gs[d] + bs[d];
  } else {
    int wi = (d - 32) / 3;
    float vn = (stats[56 + 32 + wi*3] + stats[56 + 32 + wi*3 + 1] +
                stats[56 + 32 + wi*3 + 2]) * (invN / 3.f);
    res = val * rsqrtf(vn + 1e-4f) * gv[wi];
  }
  out[idx] = res;
}

extern "C" void kernel_launch(void* const* d_in, const int* in_sizes, int n_in,
                              void* d_out, int out_size, void* d_ws, size_t ws_size,
                              hipStream_t stream) {
  const float* node_attr = (const float*)d_in[0];
  const int*   eidx      = (const int*)d_in[1];
  const float* edge_attr = (const float*)d_in[2];
  const float* edge_sh   = (const float*)d_in[3];
  const float* fc1w      = (const float*)d_in[4];
  const float* fc1b      = (const float*)d_in[5];
  const float* fc2w      = (const float*)d_in[6];
  const float* fc2b      = (const float*)d_in[7];
  const float* gs        = (const float*)d_in[8];
  const float* bs        = (const float*)d_in[9];
  const float* gv        = (const float*)d_in[10];

  float* ws = (float*)d_ws;
  float* tp    = ws;                                    // 5,600,000
  float* pre   = ws + 5600000;                          // 560,000
  float* stats = ws + 6160000;                          // 112 (pad 128)
  float* pstat = ws + 6160128;                          // 71,680
  int*   cntn  = (int*)(ws + 6231808);                  // 10,000
  int*   offs  = (int*)(ws + 6241808);                  // 10,001 (pad 10,008)
  int*   cursor= (int*)(ws + 6251816);                  // 10,000
  unsigned short* G  = (unsigned short*)(ws + 6261816); // 102,400 shorts
  unsigned short* hb = (unsigned short*)(ws + 6313016); // 6,400,000 shorts

  hipMemsetAsync(cntn, 0, (size_t)10000 * 4, stream);
  k_hidtr<<<HBLK + TBLK, 256, 0, stream>>>(edge_attr, fc1w, fc1b, fc2w, eidx, cntn, hb, G);
  k_scan<<<1, 64, 0, stream>>>(cntn, offs, cursor);
  k_tp<<<1563, 128, 0, stream>>>(hb, G, fc2b, eidx, node_attr, edge_sh, cursor, tp);
  k_gather<<<640, 256, 0, stream>>>(tp, offs, node_attr, pre, pstat);
  k_stats<<<28, 256, 0, stream>>>(pstat, stats);
  k_norm<<<(NNODES * DNODE + 255) / 256, 256, 0, stream>>>(pre, stats, gs, bs, gv, (float*)d_out);
}

// Round 6
// 318.885 us; speedup vs baseline: 1.4284x; 1.4284x over previous
//
#include <hip/hip_runtime.h>
#include <stdint.h>

#define NNODES 10000
#define NEDGES 100000
#define DNODE 56
#define JTOT 1600
#define HBLK 391   // k_hidden part blocks
#define TBLK 400   // G-transpose part blocks

typedef __attribute__((ext_vector_type(8))) short short8;
typedef __attribute__((ext_vector_type(4))) float floatx4;

__device__ __forceinline__ unsigned short f2bf(float f) {
  unsigned u = __float_as_uint(f);
  u = u + 0x7fffu + ((u >> 16) & 1u);
  return (unsigned short)(u >> 16);
}

__device__ __forceinline__ float mishf(float x) {
  float e = __expf(x);
  float z = 1.f + e; z = z * z;
  float t = (z - 1.f) / (z + 1.f);
  t = (x > 40.f) ? 1.f : t;
  return x * t;
}

// ---- fused: blocks [0,391) h = mish(ea@fc1+b1) + src histogram; [391,791) G = bf16(fc2w^T)
__global__ __launch_bounds__(256) void k_hidtr(const float* __restrict__ ea,
                                               const float* __restrict__ fc1w,
                                               const float* __restrict__ fc1b,
                                               const float* __restrict__ fc2w,
                                               const int* __restrict__ eidx,
                                               int* __restrict__ cntn,
                                               unsigned short* __restrict__ hb,
                                               unsigned short* __restrict__ G) {
  int bid = blockIdx.x;
  if (bid >= HBLK) {
    int idx = (bid - HBLK) * 256 + threadIdx.x;
    if (idx < 64 * JTOT) {
      int j = idx >> 6, k = idx & 63;
      G[idx] = f2bf(fc2w[k * JTOT + j]);
    }
    return;
  }
  int e = bid * 256 + threadIdx.x;
  if (e >= NEDGES) return;
  atomicAdd(&cntn[eidx[e]], 1);
  float a[64];
  const float4* row = (const float4*)(ea + (size_t)e * 64);
  #pragma unroll
  for (int i = 0; i < 16; i++) {
    float4 t = row[i];
    a[4*i] = t.x; a[4*i+1] = t.y; a[4*i+2] = t.z; a[4*i+3] = t.w;
  }
  for (int jb = 0; jb < 64; jb += 8) {
    float acc[8];
    #pragma unroll
    for (int i = 0; i < 8; i++) acc[i] = fc1b[jb + i];
    #pragma unroll
    for (int k = 0; k < 64; k++) {
      #pragma unroll
      for (int i = 0; i < 8; i++) acc[i] = fmaf(a[k], fc1w[k*64 + jb + i], acc[i]);
    }
    unsigned pk[4];
    #pragma unroll
    for (int i = 0; i < 4; i++) {
      unsigned lo = f2bf(mishf(acc[2*i]));
      unsigned hi = f2bf(mishf(acc[2*i+1]));
      pk[i] = lo | (hi << 16);
    }
    *(uint4*)(hb + (size_t)e*64 + jb) = make_uint4(pk[0], pk[1], pk[2], pk[3]);
  }
}

// ---- single-wave barrier-free scan
__global__ __launch_bounds__(64) void k_scan(const int* __restrict__ cntn,
                                             int* __restrict__ offs,
                                             int* __restrict__ cursor) {
  const int PER = 157;
  int lane = threadIdx.x;
  int base = lane * PER;
  int s = 0;
  for (int i = 0; i < PER; i++) {
    int idx = base + i;
    if (idx < NNODES) s += cntn[idx];
  }
  int incl = s;
  #pragma unroll
  for (int o = 1; o < 64; o <<= 1) {
    int v = __shfl_up(incl, o);
    if (lane >= o) incl += v;
  }
  int run = incl - s;
  for (int i = 0; i < PER; i++) {
    int idx = base + i;
    if (idx < NNODES) {
      offs[idx] = run; cursor[idx] = run;
      run += cntn[idx];
    }
  }
  if (lane == 63) offs[NNODES] = run;
}

// ---- fused GEMM2 + tensor product. Block = 2 waves x 32 edges. Barrier-free K-loop,
// A-frags streamed from L2 with 2-deep prefetch, fp32 coef LDS per wave.
// launch_bounds(128,2): 256-VGPR budget -- R5's (128,4) cap caused catastrophic scratch spill.
__global__ __launch_bounds__(128, 2) void k_tp(
    const unsigned short* __restrict__ hb,
    const unsigned short* __restrict__ G,
    const float* __restrict__ fc2b,
    const int* __restrict__ eidx,
    const float* __restrict__ node_attr,
    const float* __restrict__ edge_sh,
    int* __restrict__ cursor,
    float* __restrict__ tp) {
  __shared__ float b2s[JTOT];
  __shared__ float wls[2][64 * 32];    // per-wave coef table fp32: row u x 32 edges
  __shared__ int pos_s[2][32];
  const int tid = threadIdx.x;
  const int wave = tid >> 6, lane = tid & 63;
  for (int i = tid; i < JTOT; i += 128) b2s[i] = fc2b[i];

  const int e0w = blockIdx.x * 64 + wave * 32;
  float* Wt = &wls[wave][0];
  {
    int el = lane & 31, hh = lane >> 5;
    int e = e0w + el;
    bool valid = e < NEDGES;
    int dst = valid ? eidx[NEDGES + e] : 0;
    const float* na = node_attr + (size_t)dst * DNODE;
    if (hh == 0) {
      pos_s[wave][el] = valid ? atomicAdd(&cursor[eidx[e]], 1) : 0;
      #pragma unroll
      for (int u = 0; u < 32; u += 4) {
        float4 t = valid ? *(const float4*)(na + u) : make_float4(0.f,0.f,0.f,0.f);
        Wt[(u+0)*32 + el] = t.x;
        Wt[(u+1)*32 + el] = t.y;
        Wt[(u+2)*32 + el] = t.z;
        Wt[(u+3)*32 + el] = t.w;
      }
    } else {
      float4 sh = valid ? *(const float4*)(edge_sh + 4*(size_t)e) : make_float4(0.f,0.f,0.f,0.f);
      const float rs3 = 0.57735026918962576f;
      #pragma unroll
      for (int u = 0; u < 8; u++) {
        float v0 = valid ? na[32 + u*3 + 0] : 0.f;
        float v1 = valid ? na[32 + u*3 + 1] : 0.f;
        float v2 = valid ? na[32 + u*3 + 2] : 0.f;
        Wt[(32 + u*3 + 0)*32 + el] = v0;
        Wt[(32 + u*3 + 1)*32 + el] = v1;
        Wt[(32 + u*3 + 2)*32 + el] = v2;
        Wt[(56 + u)*32 + el] = (v0*sh.y + v1*sh.z + v2*sh.w) * rs3;
      }
    }
  }
  __syncthreads();   // b2s ready (Wt per-wave needs no barrier)

  const int col = lane & 15, rg = lane >> 4, rgh = rg >> 1;
  float sh0c[2], sh1c[2][3];
  bool vld[2];
  short8 bfrag[2][2];
  const short8 zfrag = {0,0,0,0,0,0,0,0};
  #pragma unroll
  for (int nt = 0; nt < 2; nt++) {
    int e = e0w + nt*16 + col;
    bool v = e < NEDGES; vld[nt] = v;
    if (v) {
      float4 sh = *(const float4*)(edge_sh + 4*(size_t)e);
      sh0c[nt] = sh.x; sh1c[nt][0] = sh.y; sh1c[nt][1] = sh.z; sh1c[nt][2] = sh.w;
      const unsigned short* hp = hb + (size_t)e * 64;
      bfrag[nt][0] = *(const short8*)(hp + rg*8);
      bfrag[nt][1] = *(const short8*)(hp + 32 + rg*8);
    } else {
      sh0c[nt] = 0.f; sh1c[nt][0] = sh1c[nt][1] = sh1c[nt][2] = 0.f;
      bfrag[nt][0] = zfrag; bfrag[nt][1] = zfrag;
    }
  }

  float sacc[2][8], vacc[2][12];
  #pragma unroll
  for (int nt = 0; nt < 2; nt++) {
    #pragma unroll
    for (int i = 0; i < 8; i++) sacc[nt][i] = 0.f;
    #pragma unroll
    for (int i = 0; i < 12; i++) vacc[nt][i] = 0.f;
  }

  auto ldpair = [&](int pp, short8& f0, short8& f1, short8& f2, short8& f3) {
    const unsigned short* q = G + (((pp*32) + col) << 6) + rg*8;
    f0 = *(const short8*)q;
    f1 = *(const short8*)(q + 32);
    f2 = *(const short8*)(q + 1024);
    f3 = *(const short8*)(q + 1024 + 32);
  };

  // 2-deep prefetch pipeline: c (current), d (next), n (next-next)
  short8 c0,c1,c2,c3, d0,d1,d2,d3, n0,n1,n2,n3;
  ldpair(0, c0, c1, c2, c3);
  ldpair(1, d0, d1, d2, d3);

  #pragma unroll 1
  for (int pp = 0; pp < 50; pp++) {
    if (pp < 48) ldpair(pp + 2, n0, n1, n2, n3);
    const int jt0 = 2*pp;
    float4 bb0 = *(const float4*)&b2s[jt0*16 + rg*4];
    float4 bb1 = *(const float4*)&b2s[(jt0+1)*16 + rg*4];
    floatx4 acc0[2], acc1[2];
    #pragma unroll
    for (int nt = 0; nt < 2; nt++) {
      floatx4 a0 = {bb0.x, bb0.y, bb0.z, bb0.w};
      a0 = __builtin_amdgcn_mfma_f32_16x16x32_bf16(c0, bfrag[nt][0], a0, 0, 0, 0);
      a0 = __builtin_amdgcn_mfma_f32_16x16x32_bf16(c1, bfrag[nt][1], a0, 0, 0, 0);
      acc0[nt] = a0;
      floatx4 a1 = {bb1.x, bb1.y, bb1.z, bb1.w};
      a1 = __builtin_amdgcn_mfma_f32_16x16x32_bf16(c2, bfrag[nt][0], a1, 0, 0, 0);
      a1 = __builtin_amdgcn_mfma_f32_16x16x32_bf16(c3, bfrag[nt][1], a1, 0, 0, 0);
      acc1[nt] = a1;
    }
    if (pp < 32) {                     // w1: u = pp
      #pragma unroll
      for (int nt = 0; nt < 2; nt++) {
        float cf = Wt[pp*32 + nt*16 + col] * sh0c[nt];
        #pragma unroll
        for (int r = 0; r < 4; r++) {
          sacc[nt][r]   = fmaf(cf, acc0[nt][r], sacc[nt][r]);
          sacc[nt][4+r] = fmaf(cf, acc1[nt][r], sacc[nt][4+r]);
        }
      }
    } else if (pp < 34) {              // w2: u = (jt-64)*2+rgh
      const int u0 = (jt0 - 64)*2 + rgh, u1 = u0 + 2;
      #pragma unroll
      for (int nt = 0; nt < 2; nt++) {
        #pragma unroll
        for (int q = 0; q < 3; q++) {
          float cf0 = Wt[(32 + u0*3 + q)*32 + nt*16 + col] * sh0c[nt];
          float cf1 = Wt[(32 + u1*3 + q)*32 + nt*16 + col] * sh0c[nt];
          #pragma unroll
          for (int r = 0; r < 4; r++) {
            vacc[nt][q*4+r] = fmaf(cf0, acc0[nt][r], vacc[nt][q*4+r]);
            vacc[nt][q*4+r] = fmaf(cf1, acc1[nt][r], vacc[nt][q*4+r]);
          }
        }
      }
    } else if (pp < 42) {              // w3: u = (jt-68)*2+rgh
      const int u0 = (jt0 - 68)*2 + rgh, u1 = u0 + 2;
      #pragma unroll
      for (int nt = 0; nt < 2; nt++) {
        float sv0 = Wt[u0*32 + nt*16 + col];
        float sv1 = Wt[u1*32 + nt*16 + col];
        #pragma unroll
        for (int q = 0; q < 3; q++) {
          float cf0 = sv0 * sh1c[nt][q];
          float cf1 = sv1 * sh1c[nt][q];
          #pragma unroll
          for (int r = 0; r < 4; r++) {
            vacc[nt][q*4+r] = fmaf(cf0, acc0[nt][r], vacc[nt][q*4+r]);
            vacc[nt][q*4+r] = fmaf(cf1, acc1[nt][r], vacc[nt][q*4+r]);
          }
        }
      }
    } else {                           // w4: u = pp-42
      const int u = pp - 42;
      #pragma unroll
      for (int nt = 0; nt < 2; nt++) {
        float cf = Wt[(56 + u)*32 + nt*16 + col];
        #pragma unroll
        for (int r = 0; r < 4; r++) {
          sacc[nt][r]   = fmaf(cf, acc0[nt][r], sacc[nt][r]);
          sacc[nt][4+r] = fmaf(cf, acc1[nt][r], sacc[nt][4+r]);
        }
      }
    }
    c0 = d0; c1 = d1; c2 = d2; c3 = d3;
    d0 = n0; d1 = n1; d2 = n2; d3 = n3;
  }

  // ---- epilogue: direct stores
  const float ascale = 0.15811388300841897f;   // 1/sqrt(40)
  #pragma unroll
  for (int nt = 0; nt < 2; nt++) {
    int el = nt*16 + col;
    float* rowp = tp + (size_t)pos_s[wave][el] * DNODE;
    if (vld[nt]) {
      #pragma unroll
      for (int p = 0; p < 2; p++) {
        float4 v = make_float4(ascale*sacc[nt][p*4+0], ascale*sacc[nt][p*4+1],
                               ascale*sacc[nt][p*4+2], ascale*sacc[nt][p*4+3]);
        *(float4*)(rowp + p*16 + rg*4) = v;
      }
    }
    float vtot[12];
    #pragma unroll
    for (int k = 0; k < 12; k++)
      vtot[k] = (vacc[nt][k] + __shfl_xor(vacc[nt][k], 32)) * ascale;
    if (rg < 2 && vld[nt]) {
      float tmp[12];
      #pragma unroll
      for (int q = 0; q < 3; q++)
        #pragma unroll
        for (int r = 0; r < 4; r++) tmp[r*3 + q] = vtot[q*4 + r];
      #pragma unroll
      for (int j = 0; j < 3; j++)
        *(float4*)(rowp + 32 + (rg & 1)*12 + j*4) = *(float4*)&tmp[j*4];
    }
  }
}

// ---- per-node mean + residual + BN partials (contiguous CSR rows)
__global__ __launch_bounds__(256) void k_gather(const float* __restrict__ tp,
                                                const int* __restrict__ offs,
                                                const float* __restrict__ node_attr,
                                                float* __restrict__ pre,
                                                float* __restrict__ pstat) {
  __shared__ float redS[4*64], redQ[4*64];
  int t = threadIdx.x, wave = t >> 6, lane = t & 63;
  int gw = blockIdx.x * 4 + wave;
  const int W = 640 * 4;
  int off = (lane < DNODE) ? lane : 0;
  float ssum = 0.f, ssq = 0.f;
  for (int n = gw; n < NNODES; n += W) {
    int beg = offs[n], end = offs[n+1];
    float acc = 0.f;
    int i = beg;
    for (; i + 4 <= end; i += 4) {
      float v0 = tp[(size_t)(i+0)*DNODE + off];
      float v1 = tp[(size_t)(i+1)*DNODE + off];
      float v2 = tp[(size_t)(i+2)*DNODE + off];
      float v3 = tp[(size_t)(i+3)*DNODE + off];
      acc += (v0 + v1) + (v2 + v3);
    }
    for (; i < end; i++) acc += tp[(size_t)i*DNODE + off];
    int c = end - beg; if (c < 1) c = 1;
    float m = acc / (float)c + node_attr[(size_t)n*DNODE + off];
    if (lane < DNODE) { pre[(size_t)n*DNODE + lane] = m; ssum += m; ssq += m*m; }
  }
  redS[wave*64 + lane] = ssum;
  redQ[wave*64 + lane] = ssq;
  __syncthreads();
  if (wave == 0 && lane < DNODE) {
    float a = redS[lane] + redS[64+lane] + redS[128+lane] + redS[192+lane];
    float b = redQ[lane] + redQ[64+lane] + redQ[128+lane] + redQ[192+lane];
    pstat[(size_t)blockIdx.x*112 + lane] = a;
    pstat[(size_t)blockIdx.x*112 + 56 + lane] = b;
  }
}

__global__ __launch_bounds__(256) void k_stats(const float* __restrict__ pstat,
                                               float* __restrict__ stats) {
  int f = blockIdx.x * 4 + (threadIdx.x >> 6);
  int lane = threadIdx.x & 63;
  float v = 0.f;
  for (int b = lane; b < 640; b += 64) v += pstat[(size_t)b*112 + f];
  #pragma unroll
  for (int o = 32; o; o >>= 1) v += __shfl_xor(v, o);
  if (lane == 0) stats[f] = v;
}

__global__ __launch_bounds__(256) void k_norm(const float* __restrict__ pre,
                                              const float* __restrict__ stats,
                                              const float* __restrict__ gs,
                                              const float* __restrict__ bs,
                                              const float* __restrict__ gv,
                                              float* __restrict__ out) {
  int idx = blockIdx.x * 256 + threadIdx.x;
  if (idx >= NNODES * DNODE) return;
  int n = idx / DNODE;
  int d = idx - n * DNODE;
  float val = pre[idx];
  const float invN = 1.f / (float)NNODES;
  float res;
  if (d < 32) {
    float mu = stats[d] * invN;
    float var = stats[56 + d] * invN - mu * mu;
    res = (val - mu) * rsqrtf(var + 1e-4f) * gs[d] + bs[d];
  } else {
    int wi = (d - 32) / 3;
    float vn = (stats[56 + 32 + wi*3] + stats[56 + 32 + wi*3 + 1] +
                stats[56 + 32 + wi*3 + 2]) * (invN / 3.f);
    res = val * rsqrtf(vn + 1e-4f) * gv[wi];
  }
  out[idx] = res;
}

extern "C" void kernel_launch(void* const* d_in, const int* in_sizes, int n_in,
                              void* d_out, int out_size, void* d_ws, size_t ws_size,
                              hipStream_t stream) {
  const float* node_attr = (const float*)d_in[0];
  const int*   eidx      = (const int*)d_in[1];
  const float* edge_attr = (const float*)d_in[2];
  const float* edge_sh   = (const float*)d_in[3];
  const float* fc1w      = (const float*)d_in[4];
  const float* fc1b      = (const float*)d_in[5];
  const float* fc2w      = (const float*)d_in[6];
  const float* fc2b      = (const float*)d_in[7];
  const float* gs        = (const float*)d_in[8];
  const float* bs        = (const float*)d_in[9];
  const float* gv        = (const float*)d_in[10];

  float* ws = (float*)d_ws;
  float* tp    = ws;                                    // 5,600,000
  float* pre   = ws + 5600000;                          // 560,000
  float* stats = ws + 6160000;                          // 112 (pad 128)
  float* pstat = ws + 6160128;                          // 71,680
  int*   cntn  = (int*)(ws + 6231808);                  // 10,000
  int*   offs  = (int*)(ws + 6241808);                  // 10,001 (pad 10,008)
  int*   cursor= (int*)(ws + 6251816);                  // 10,000
  unsigned short* G  = (unsigned short*)(ws + 6261816); // 102,400 shorts
  unsigned short* hb = (unsigned short*)(ws + 6313016); // 6,400,000 shorts

  hipMemsetAsync(cntn, 0, (size_t)10000 * 4, stream);
  k_hidtr<<<HBLK + TBLK, 256, 0, stream>>>(edge_attr, fc1w, fc1b, fc2w, eidx, cntn, hb, G);
  k_scan<<<1, 64, 0, stream>>>(cntn, offs, cursor);
  k_tp<<<1563, 128, 0, stream>>>(hb, G, fc2b, eidx, node_attr, edge_sh, cursor, tp);
  k_gather<<<640, 256, 0, stream>>>(tp, offs, node_attr, pre, pstat);
  k_stats<<<28, 256, 0, stream>>>(pstat, stats);
  k_norm<<<(NNODES * DNODE + 255) / 256, 256, 0, stream>>>(pre, stats, gs, bs, gv, (float*)d_out);
}